// Round 7
// baseline (3721.598 us; speedup 1.0000x reference)
//
#include <hip/hip_runtime.h>
#include <hip/hip_bf16.h>
#include <cstdint>
#include <cstddef>

#define T_LEN 512
#define B_SZ  512
#define F_IN  64
#define H_DIM 128
#define NSTEP 8
#define T_CHUNK 64   // chunk rows = 64*512 = 32768 -> 256 m-tiles of 128

typedef __attribute__((ext_vector_type(8))) short short8;
typedef __attribute__((ext_vector_type(4))) float f32x4;

__device__ __forceinline__ float fsig(float x) { return 1.0f / (1.0f + __expf(-x)); }
__device__ __forceinline__ float ftanh(float x) {
  float e = __expf(-2.0f * fabsf(x));
  float t = (1.0f - e) / (1.0f + e);
  return copysignf(t, x);
}
__device__ __forceinline__ unsigned short bf16hi(float x) {
  __hip_bfloat16 h = __float2bfloat16(x);
  return *(unsigned short*)&h;
}
__device__ __forceinline__ float bf2f(unsigned short u) {
  return __uint_as_float(((unsigned)u) << 16);
}
__device__ __forceinline__ float bflo(unsigned u) { return __uint_as_float(u << 16); }
__device__ __forceinline__ float bfhi(unsigned u) { return __uint_as_float(u & 0xffff0000u); }

// DPP cross-lane add within 16-lane rows: xor1, xor2, ror4, ror8
template <int CTRL>
__device__ __forceinline__ float dpp_add(float v) {
  int p = __builtin_amdgcn_update_dpp(0, __float_as_int(v), CTRL, 0xF, 0xF, true);
  return v + __int_as_float(p);
}
__device__ __forceinline__ float row_sum16(float v) {
  v = dpp_add<0xB1>(v);
  v = dpp_add<0x4E>(v);
  v = dpp_add<0x124>(v);
  v = dpp_add<0x128>(v);
  return v;
}

// padded h index for rec LDS
__device__ __forceinline__ int hidx(int k) { return (k >> 3) * 12 + (k & 7); }

// -------------------------------------------------------------------------
// Split the 3 encoder w_ih matrices into bf16 hi/lo pairs (one-time prep).
// -------------------------------------------------------------------------
__global__ __launch_bounds__(256) void prep_split(
    const float* __restrict__ w0, const float* __restrict__ w1,
    const float* __restrict__ w2,
    unsigned short* __restrict__ hi, unsigned short* __restrict__ lo)
{
  const int i = blockIdx.x * 256 + threadIdx.x;
  if (i >= 122880) return;
  float v = (i < 24576) ? w0[i] : ((i < 73728) ? w1[i - 24576] : w2[i - 73728]);
  const unsigned short h = bf16hi(v);
  hi[i] = h;
  lo[i] = bf16hi(v - bf2f(h));
}

// -------------------------------------------------------------------------
// Fused encoder step: blocks [0,256) = rec(chunk j) ; blocks [256,1024) =
// gx GEMM for the NEXT chunk (double-buffered gx). 768 threads both roles.
// gx role: waves 4-11 stage A/B tiles, waves 0-3 run MFMA (128x128 tile,
// 3 n-blocks via blockIdx). rec role: R4/R6 DPP-reduce recurrence.
// -------------------------------------------------------------------------
struct RecS {
  float hs[2][196];
  float ghs[2][384];
  float gxs[2][2][384];
  float bhl[384];
};
struct GxS {
  unsigned short Ah[128 * 40], Al[128 * 40];
  unsigned short Bh[128 * 40], Bl[128 * 40];
};
union FusedLDS { RecS r; GxS g; };

__global__ __launch_bounds__(768, 3) void enc_fused(
    // gx role args
    const float* __restrict__ x,
    const unsigned short* __restrict__ Hhi, const unsigned short* __restrict__ Hlo,
    const unsigned short* __restrict__ Whi, const unsigned short* __restrict__ Wlo,
    const float* __restrict__ b_ih, float* __restrict__ gx_out,
    int gx_t0, int gx_kdim, int gx_isl0, int do_gx,
    // rec role args
    const float* __restrict__ gx_in,
    const float* __restrict__ w_hh, const float* __restrict__ b_hh,
    float* __restrict__ h_state, int rec_t0, int rec_chunk0, int do_rec)
{
  __shared__ FusedLDS lds;
  const int tid = threadIdx.x;

  if (blockIdx.x < 256) {
    // ===================== rec role =====================
    if (!do_rec) return;
    RecS& R = lds.r;
    const int wave = tid >> 6, lane = tid & 63;
    const int jg = lane >> 4, ks = lane & 15;
    const int J0 = (wave * 4 + jg) * 8;
    const int b0 = blockIdx.x * 2;
    const int gr = (tid >= 384) ? 1 : 0;
    const int gidx = tid - (gr ? 384 : 0);

    float4 w[8][2];
    #pragma unroll
    for (int jj = 0; jj < 8; ++jj) {
      const float* wp = &w_hh[(size_t)(J0 + jj) * 128 + ks * 8];
      w[jj][0] = *(const float4*)&wp[0];
      w[jj][1] = *(const float4*)&wp[4];
    }
    if (tid < 384) R.bhl[tid] = b_hh[tid];
    if (tid < 256) {
      const int r = tid >> 7, c = tid & 127;
      R.hs[r][hidx(c)] = rec_chunk0 ? 0.0f : h_state[(size_t)(b0 + r) * 128 + c];
    }
    R.gxs[0][gr][gidx] = gx_in[(size_t)(b0 + gr) * 384 + gidx];
    __syncthreads();

    for (int tl = 0; tl < T_CHUNK; ++tl) {
      float gxn = 0.0f;
      if (tl + 1 < T_CHUNK)
        gxn = gx_in[((size_t)(tl + 1) * B_SZ + b0 + gr) * 384 + gidx];

      const float4 h00 = *(const float4*)&R.hs[0][ks * 12];
      const float4 h01 = *(const float4*)&R.hs[0][ks * 12 + 4];
      const float4 h10 = *(const float4*)&R.hs[1][ks * 12];
      const float4 h11 = *(const float4*)&R.hs[1][ks * 12 + 4];
      float a0[8], a1[8];
      #pragma unroll
      for (int jj = 0; jj < 8; ++jj) {
        a0[jj] = h00.x * w[jj][0].x + h00.y * w[jj][0].y
               + h00.z * w[jj][0].z + h00.w * w[jj][0].w
               + h01.x * w[jj][1].x + h01.y * w[jj][1].y
               + h01.z * w[jj][1].z + h01.w * w[jj][1].w;
        a1[jj] = h10.x * w[jj][0].x + h10.y * w[jj][0].y
               + h10.z * w[jj][0].z + h10.w * w[jj][0].w
               + h11.x * w[jj][1].x + h11.y * w[jj][1].y
               + h11.z * w[jj][1].z + h11.w * w[jj][1].w;
      }
      #pragma unroll
      for (int jj = 0; jj < 8; ++jj) {
        a0[jj] = row_sum16(a0[jj]);
        a1[jj] = row_sum16(a1[jj]);
      }
      if (ks == 0) {
        *(float4*)&R.ghs[0][J0]     = make_float4(a0[0], a0[1], a0[2], a0[3]);
        *(float4*)&R.ghs[0][J0 + 4] = make_float4(a0[4], a0[5], a0[6], a0[7]);
        *(float4*)&R.ghs[1][J0]     = make_float4(a1[0], a1[1], a1[2], a1[3]);
        *(float4*)&R.ghs[1][J0 + 4] = make_float4(a1[4], a1[5], a1[6], a1[7]);
      }
      R.gxs[(tl + 1) & 1][gr][gidx] = gxn;
      __syncthreads();

      if (tid < 256) {
        const int rr = tid >> 7, c = tid & 127;
        const float* gxp = R.gxs[tl & 1][rr];
        const float rg = fsig(gxp[c]       + R.ghs[rr][c]       + R.bhl[c]);
        const float zg = fsig(gxp[128 + c] + R.ghs[rr][128 + c] + R.bhl[128 + c]);
        const float ng = ftanh(gxp[256 + c] + rg * (R.ghs[rr][256 + c] + R.bhl[256 + c]));
        const float hn = (1.0f - zg) * ng + zg * R.hs[rr][hidx(c)];
        R.hs[rr][hidx(c)] = hn;
        const size_t ob = ((size_t)(rec_t0 + tl) * B_SZ + (b0 + rr)) * 128 + c;
        const unsigned short hh = bf16hi(hn);
        // const_cast: H buffers are writable ws; passed const for gx reads
        ((unsigned short*)Hhi)[ob] = hh;
        ((unsigned short*)Hlo)[ob] = bf16hi(hn - bf2f(hh));
      }
      __syncthreads();
    }
    if (tid < 256) {
      const int r = tid >> 7, c = tid & 127;
      h_state[(size_t)(b0 + r) * 128 + c] = R.hs[r][hidx(c)];
    }
  } else {
    // ===================== gx role =====================
    if (!do_gx) return;
    GxS& G = lds.g;
    const int gb = blockIdx.x - 256;            // [0, 768)
    const int m0 = (gb & 255) * 128;
    const int n0 = (gb >> 8) * 128;
    const int wave = tid >> 6, lane = tid & 63;
    const int quad = lane >> 4, l16 = lane & 15;
    const int wm = (wave & 1) * 64;
    const int wn = ((wave >> 1) & 1) * 64;
    const size_t row0 = (size_t)gx_t0 * B_SZ + m0;

    f32x4 acc[4][4];
    #pragma unroll
    for (int i = 0; i < 4; ++i)
      #pragma unroll
      for (int j = 0; j < 4; ++j) acc[i][j] = (f32x4){0.f, 0.f, 0.f, 0.f};

    float bias[4];
    if (tid < 256) {
      #pragma unroll
      for (int nt = 0; nt < 4; ++nt) bias[nt] = b_ih[n0 + wn + nt * 16 + l16];
    }

    for (int kc = 0; kc < gx_kdim; kc += 32) {
      __syncthreads();
      if (tid >= 256) {
        const int g = tid - 256;                // [0,512)
        if (gx_isl0) {
          // fp32 x -> split bf16; 1024 float4 groups, 2 per staging thread
          #pragma unroll
          for (int gg = g; gg < 1024; gg += 512) {
            const int r = gg >> 3, c4 = (gg & 7) * 4;
            const int m = m0 + r;
            const int tg = gx_t0 + (m >> 9), bb = m & 511;
            const float4 v = *(const float4*)&x[((size_t)bb * T_LEN + tg) * 64 + kc + c4];
            const unsigned short h0 = bf16hi(v.x), h1 = bf16hi(v.y),
                                 h2 = bf16hi(v.z), h3 = bf16hi(v.w);
            ushort4 hv; hv.x = h0; hv.y = h1; hv.z = h2; hv.w = h3;
            ushort4 lv;
            lv.x = bf16hi(v.x - bf2f(h0)); lv.y = bf16hi(v.y - bf2f(h1));
            lv.z = bf16hi(v.z - bf2f(h2)); lv.w = bf16hi(v.w - bf2f(h3));
            *(ushort4*)&G.Ah[r * 40 + c4] = hv;
            *(ushort4*)&G.Al[r * 40 + c4] = lv;
          }
        } else {
          const int r = g >> 2, c8 = (g & 3) * 8;
          const size_t src = (row0 + r) * gx_kdim + kc + c8;
          *(uint4*)&G.Ah[r * 40 + c8] = *(const uint4*)&Hhi[src];
          *(uint4*)&G.Al[r * 40 + c8] = *(const uint4*)&Hlo[src];
        }
        {
          const int r = g >> 2, c8 = (g & 3) * 8;
          const size_t src = (size_t)(n0 + r) * gx_kdim + kc + c8;
          *(uint4*)&G.Bh[r * 40 + c8] = *(const uint4*)&Whi[src];
          *(uint4*)&G.Bl[r * 40 + c8] = *(const uint4*)&Wlo[src];
        }
      }
      __syncthreads();
      if (tid < 256) {
        short8 ah[4], al[4], bh[4], bl[4];
        #pragma unroll
        for (int mt = 0; mt < 4; ++mt) {
          ah[mt] = *(const short8*)&G.Ah[(wm + mt * 16 + l16) * 40 + quad * 8];
          al[mt] = *(const short8*)&G.Al[(wm + mt * 16 + l16) * 40 + quad * 8];
        }
        #pragma unroll
        for (int nt = 0; nt < 4; ++nt) {
          bh[nt] = *(const short8*)&G.Bh[(wn + nt * 16 + l16) * 40 + quad * 8];
          bl[nt] = *(const short8*)&G.Bl[(wn + nt * 16 + l16) * 40 + quad * 8];
        }
        #pragma unroll
        for (int mt = 0; mt < 4; ++mt) {
          #pragma unroll
          for (int nt = 0; nt < 4; ++nt) {
            acc[mt][nt] = __builtin_amdgcn_mfma_f32_16x16x32_bf16(ah[mt], bh[nt], acc[mt][nt], 0, 0, 0);
            acc[mt][nt] = __builtin_amdgcn_mfma_f32_16x16x32_bf16(ah[mt], bl[nt], acc[mt][nt], 0, 0, 0);
            acc[mt][nt] = __builtin_amdgcn_mfma_f32_16x16x32_bf16(al[mt], bh[nt], acc[mt][nt], 0, 0, 0);
          }
        }
      }
    }
    if (tid < 256) {
      #pragma unroll
      for (int mt = 0; mt < 4; ++mt) {
        #pragma unroll
        for (int nt = 0; nt < 4; ++nt) {
          #pragma unroll
          for (int reg = 0; reg < 4; ++reg) {
            const int m = m0 + wm + mt * 16 + quad * 4 + reg;
            const int n = n0 + wn + nt * 16 + l16;
            gx_out[(size_t)m * 384 + n] = acc[mt][nt][reg] + bias[nt];
          }
        }
      }
    }
  }
}

// -------------------------------------------------------------------------
// keys = H @ aWk^T + abk, split-bf16 MFMA, output Khi (bf16 RNE) only.
// -------------------------------------------------------------------------
__global__ __launch_bounds__(256) void keys_gemm(
    const unsigned short* __restrict__ Ahi, const unsigned short* __restrict__ Alo,
    const float* __restrict__ aWk, const float* __restrict__ abk,
    unsigned short* __restrict__ Khi)
{
  __shared__ unsigned short Ah[64 * 40], Al[64 * 40];
  __shared__ unsigned short Bh[128 * 136], Bl[128 * 136];
  const int tid  = threadIdx.x;
  const int wave = tid >> 6, lane = tid & 63;
  const int quad = lane >> 4, l16 = lane & 15;
  const size_t m0 = (size_t)blockIdx.x * 64;

  for (int i = tid; i < 16384; i += 256) {
    const float v = aWk[i];
    const unsigned short h = bf16hi(v);
    const int r = i >> 7, k = i & 127;
    Bh[r * 136 + k] = h;
    Bl[r * 136 + k] = bf16hi(v - bf2f(h));
  }

  f32x4 acc[8];
  #pragma unroll
  for (int i = 0; i < 8; ++i) acc[i] = (f32x4){0.f, 0.f, 0.f, 0.f};
  float bias[8];
  #pragma unroll
  for (int nt = 0; nt < 8; ++nt) bias[nt] = abk[nt * 16 + l16];

  const int r = tid >> 2, c8 = (tid & 3) * 8;
  for (int kc = 0; kc < 128; kc += 32) {
    __syncthreads();
    const size_t src = (m0 + r) * 128 + kc + c8;
    *(uint4*)&Ah[r * 40 + c8] = *(const uint4*)&Ahi[src];
    *(uint4*)&Al[r * 40 + c8] = *(const uint4*)&Alo[src];
    __syncthreads();
    const short8 a_hi = *(const short8*)&Ah[(wave * 16 + l16) * 40 + quad * 8];
    const short8 a_lo = *(const short8*)&Al[(wave * 16 + l16) * 40 + quad * 8];
    #pragma unroll
    for (int nt = 0; nt < 8; ++nt) {
      const short8 b_hi = *(const short8*)&Bh[(nt * 16 + l16) * 136 + kc + quad * 8];
      const short8 b_lo = *(const short8*)&Bl[(nt * 16 + l16) * 136 + kc + quad * 8];
      acc[nt] = __builtin_amdgcn_mfma_f32_16x16x32_bf16(a_hi, b_hi, acc[nt], 0, 0, 0);
      acc[nt] = __builtin_amdgcn_mfma_f32_16x16x32_bf16(a_hi, b_lo, acc[nt], 0, 0, 0);
      acc[nt] = __builtin_amdgcn_mfma_f32_16x16x32_bf16(a_lo, b_hi, acc[nt], 0, 0, 0);
    }
  }
  #pragma unroll
  for (int nt = 0; nt < 8; ++nt) {
    #pragma unroll
    for (int reg = 0; reg < 4; ++reg) {
      const size_t m = m0 + wave * 16 + quad * 4 + reg;
      const int n = nt * 16 + l16;
      Khi[m * 128 + n] = bf16hi(acc[nt][reg] + bias[nt]);
    }
  }
}

// -------------------------------------------------------------------------
// Decoder: one block per batch row, 512 threads, 8 steps in-kernel.
// K (bf16) and H (bf16-hi for ctx, hi+lo for h0) in (T,B,H).
// -------------------------------------------------------------------------
__global__ __launch_bounds__(512) void decoder(
    const unsigned short* __restrict__ Hhi, const unsigned short* __restrict__ Hlo,
    const unsigned short* __restrict__ Khi,
    const float* __restrict__ aWq, const float* __restrict__ abq,
    const float* __restrict__ av,
    const float* __restrict__ dwih, const float* __restrict__ dwhh,
    const float* __restrict__ dbih, const float* __restrict__ dbhh,
    const float* __restrict__ lng, const float* __restrict__ lnb,
    const float* __restrict__ w1, const float* __restrict__ b1,
    const float* __restrict__ w2, const float* __restrict__ b2,
    float* __restrict__ out)
{
  __shared__ float h_s[128], q_s[128], av_s[128], s_s[512], w_s[512];
  __shared__ float part[8][128], u_s[256], gx_s[384], gh_s[384], y_s[128];
  __shared__ float red[16];
  const int b = blockIdx.x, tid = threadIdx.x;
  const int wave = tid >> 6, lane = tid & 63;
  const int tslot = lane >> 4, ks = lane & 15;

  if (tid < 128) {
    const size_t base = ((size_t)(T_LEN - 1) * B_SZ + b) * 128 + tid;
    h_s[tid] = bf2f(Hhi[base]) + bf2f(Hlo[base]);
    av_s[tid] = av[tid];
  }
  __syncthreads();

  for (int step = 0; step < NSTEP; ++step) {
    if (tid < 128) {
      float acc = abq[tid];
      const float* wr = &aWq[(size_t)tid * 128];
      #pragma unroll 8
      for (int k4 = 0; k4 < 32; ++k4) {
        const float4 hv = *(const float4*)&h_s[k4 * 4];
        const float4 wv = *(const float4*)&wr[k4 * 4];
        acc += hv.x * wv.x + hv.y * wv.y + hv.z * wv.z + hv.w * wv.w;
      }
      q_s[tid] = acc;
    }
    __syncthreads();
    // scores: 16-lane rows cooperatively dot one key row (bf16 K, 128 B/row)
    #pragma unroll 2
    for (int it = 0; it < 16; ++it) {
      const int t = it * 32 + wave * 4 + tslot;
      const size_t kb = ((size_t)t * B_SZ + b) * 128 + ks * 8;
      const uint4 uh = *(const uint4*)&Khi[kb];
      const float4 q0 = *(const float4*)&q_s[ks * 8];
      const float4 q1 = *(const float4*)&q_s[ks * 8 + 4];
      const float4 a0 = *(const float4*)&av_s[ks * 8];
      const float4 a1 = *(const float4*)&av_s[ks * 8 + 4];
      float acc = ftanh(bflo(uh.x) + q0.x) * a0.x + ftanh(bfhi(uh.x) + q0.y) * a0.y
                + ftanh(bflo(uh.y) + q0.z) * a0.z + ftanh(bfhi(uh.y) + q0.w) * a0.w
                + ftanh(bflo(uh.z) + q1.x) * a1.x + ftanh(bfhi(uh.z) + q1.y) * a1.y
                + ftanh(bflo(uh.w) + q1.z) * a1.z + ftanh(bfhi(uh.w) + q1.w) * a1.w;
      acc = row_sum16(acc);
      if (ks == 0) s_s[t] = acc;
    }
    __syncthreads();
    // softmax over 512
    {
      const float sv = s_s[tid];
      float mx = sv;
      #pragma unroll
      for (int o = 32; o; o >>= 1) mx = fmaxf(mx, __shfl_xor(mx, o, 64));
      if (lane == 0) red[wave] = mx;
      __syncthreads();
      mx = red[0];
      #pragma unroll
      for (int i = 1; i < 8; ++i) mx = fmaxf(mx, red[i]);
      const float e = __expf(sv - mx);
      float sm = e;
      #pragma unroll
      for (int o = 32; o; o >>= 1) sm += __shfl_xor(sm, o, 64);
      if (lane == 0) red[8 + wave] = sm;
      __syncthreads();
      float tot = red[8];
      #pragma unroll
      for (int i = 1; i < 8; ++i) tot += red[8 + i];
      w_s[tid] = e / tot;
    }
    __syncthreads();
    // ctx = sum_t w[t] * H[t,b,:]  (bf16-hi H, packed uint = 2 channels/lane)
    {
      const int th = tid >> 6;
      const int c2 = (tid & 63) * 2;
      float acc0 = 0.0f, acc1 = 0.0f;
      #pragma unroll 4
      for (int q = 0; q < 64; ++q) {
        const int t = th * 64 + q;
        const unsigned u = *(const unsigned*)&Hhi[((size_t)t * B_SZ + b) * 128 + c2];
        const float wt = w_s[t];
        acc0 += wt * bflo(u);
        acc1 += wt * bfhi(u);
      }
      part[th][c2] = acc0;
      part[th][c2 + 1] = acc1;
    }
    __syncthreads();
    if (tid < 128) {
      float s = part[0][tid];
      #pragma unroll
      for (int i = 1; i < 8; ++i) s += part[i][tid];
      u_s[tid] = s;
      u_s[128 + tid] = h_s[tid];
    }
    __syncthreads();
    if (tid < 384) {
      const int j = tid;
      float gxv = dbih[j], ghv = dbhh[j];
      const float* wxr = &dwih[(size_t)j * 256];
      const float* whr = &dwhh[(size_t)j * 128];
      #pragma unroll 8
      for (int k4 = 0; k4 < 64; ++k4) {
        const float4 uv = *(const float4*)&u_s[k4 * 4];
        const float4 wv = *(const float4*)&wxr[k4 * 4];
        gxv += uv.x * wv.x + uv.y * wv.y + uv.z * wv.z + uv.w * wv.w;
      }
      #pragma unroll 8
      for (int k4 = 0; k4 < 32; ++k4) {
        const float4 hv = *(const float4*)&h_s[k4 * 4];
        const float4 wv = *(const float4*)&whr[k4 * 4];
        ghv += hv.x * wv.x + hv.y * wv.y + hv.z * wv.z + hv.w * wv.w;
      }
      gx_s[j] = gxv; gh_s[j] = ghv;
    }
    __syncthreads();
    if (tid < 128) {
      const float r = fsig(gx_s[tid] + gh_s[tid]);
      const float z = fsig(gx_s[128 + tid] + gh_s[128 + tid]);
      const float n = ftanh(gx_s[256 + tid] + r * gh_s[256 + tid]);
      const float hn = (1.0f - z) * n + z * h_s[tid];
      h_s[tid] = hn;
      float s1 = hn, s2 = hn * hn;
      #pragma unroll
      for (int o = 32; o; o >>= 1) { s1 += __shfl_xor(s1, o, 64); s2 += __shfl_xor(s2, o, 64); }
      if ((tid & 63) == 0) { red[tid >> 6] = s1; red[4 + (tid >> 6)] = s2; }
    }
    __syncthreads();
    if (tid < 128) {
      const float hn  = h_s[tid];
      const float mu  = (red[0] + red[1]) * (1.0f / 128.0f);
      const float var = (red[4] + red[5]) * (1.0f / 128.0f) - mu * mu;
      y_s[tid] = (hn - mu) / sqrtf(var + 1e-5f) * lng[tid] + lnb[tid];
    }
    __syncthreads();
    if (tid < 64) {
      float acc = b1[tid];
      const float* wr = &w1[(size_t)tid * 128];
      #pragma unroll 8
      for (int k4 = 0; k4 < 32; ++k4) {
        const float4 yv = *(const float4*)&y_s[k4 * 4];
        const float4 wv = *(const float4*)&wr[k4 * 4];
        acc += yv.x * wv.x + yv.y * wv.y + yv.z * wv.z + yv.w * wv.w;
      }
      acc = fmaxf(acc, 0.0f);
      float v = acc * w2[tid];
      #pragma unroll
      for (int o = 32; o; o >>= 1) v += __shfl_xor(v, o, 64);
      if (tid == 0) out[(size_t)b * NSTEP + step] = v + b2[0];
    }
    __syncthreads();
  }
}

// -------------------------------------------------------------------------
extern "C" void kernel_launch(void* const* d_in, const int* in_sizes, int n_in,
                              void* d_out, int out_size, void* d_ws, size_t ws_size,
                              hipStream_t stream)
{
  (void)in_sizes; (void)n_in; (void)out_size; (void)ws_size;
  const float* x    = (const float*)d_in[0];
  const float* ewih[3] = {(const float*)d_in[1], (const float*)d_in[5], (const float*)d_in[9]};
  const float* ewhh[3] = {(const float*)d_in[2], (const float*)d_in[6], (const float*)d_in[10]};
  const float* ebih[3] = {(const float*)d_in[3], (const float*)d_in[7], (const float*)d_in[11]};
  const float* ebhh[3] = {(const float*)d_in[4], (const float*)d_in[8], (const float*)d_in[12]};
  const float* aWq  = (const float*)d_in[13];
  const float* abq  = (const float*)d_in[14];
  const float* aWk  = (const float*)d_in[15];
  const float* abk  = (const float*)d_in[16];
  const float* av   = (const float*)d_in[17];
  const float* dwih = (const float*)d_in[18];
  const float* dwhh = (const float*)d_in[19];
  const float* dbih = (const float*)d_in[20];
  const float* dbhh = (const float*)d_in[21];
  const float* lng  = (const float*)d_in[22];
  const float* lnb  = (const float*)d_in[23];
  const float* w1   = (const float*)d_in[24];
  const float* b1   = (const float*)d_in[25];
  const float* w2   = (const float*)d_in[26];
  const float* b2   = (const float*)d_in[27];

  char* base = (char*)d_ws;
  unsigned short* Hhi = (unsigned short*)base;                    // 64 MiB (T,B,H)
  unsigned short* Hlo = (unsigned short*)(base + 67108864);       // 64 MiB
  float* gxb[2] = { (float*)(base + 134217728),                   // 48 MiB
                    (float*)(base + 184549376) };                 // 48 MiB
  float* h_state = (float*)(base + 234881024);                    // 256 KiB
  unsigned short* Whi = (unsigned short*)(base + 235143168);      // 240 KiB
  unsigned short* Wlo = (unsigned short*)(base + 235388928);      // 240 KiB
  unsigned short* Khi = (unsigned short*)(base + 134217728);      // decode: 64 MiB over gx bufs

  prep_split<<<dim3(480), dim3(256), 0, stream>>>(ewih[0], ewih[1], ewih[2], Whi, Wlo);

  const int koff[3] = {0, 24576, 73728};
  const int kdim[3] = {64, 128, 128};
  const int NCH = T_LEN / T_CHUNK;        // 8 chunks/layer
  const int NSEQ = 3 * NCH;               // 24

  for (int i = 0; i <= NSEQ; ++i) {
    const int gx_on = (i < NSEQ);
    const int rec_on = (i > 0);
    const int lg = gx_on ? (i / NCH) : 0;
    const int cg = gx_on ? (i % NCH) : 0;
    const int lr = rec_on ? ((i - 1) / NCH) : 0;
    const int cr = rec_on ? ((i - 1) % NCH) : 0;
    enc_fused<<<dim3(1024), dim3(768), 0, stream>>>(
        x, Hhi, Hlo, Whi + koff[lg], Wlo + koff[lg], ebih[lg],
        gxb[i & 1], cg * T_CHUNK, kdim[lg], (lg == 0) ? 1 : 0, gx_on,
        gxb[(i - 1) & 1], ewhh[lr], ebhh[lr],
        h_state, cr * T_CHUNK, (cr == 0) ? 1 : 0, rec_on);
  }

  keys_gemm<<<dim3(4096), dim3(256), 0, stream>>>(Hhi, Hlo, aWk, abk, Khi);
  decoder<<<dim3(512), dim3(512), 0, stream>>>(
      Hhi, Hlo, Khi, aWq, abq, av, dwih, dwhh, dbih, dbhh,
      lng, lnb, w1, b1, w2, b2, (float*)d_out);
}

// Round 8
// 3288.345 us; speedup vs baseline: 1.1318x; 1.1318x over previous
//
#include <hip/hip_runtime.h>
#include <hip/hip_bf16.h>
#include <cstdint>
#include <cstddef>

#define T_LEN 512
#define B_SZ  512
#define F_IN  64
#define H_DIM 128
#define NSTEP 8
#define T_CHUNK 128

typedef __attribute__((ext_vector_type(8))) short short8;
typedef __attribute__((ext_vector_type(4))) float f32x4;

__device__ __forceinline__ float fsig(float x) { return 1.0f / (1.0f + __expf(-x)); }
__device__ __forceinline__ float ftanh(float x) {
  float e = __expf(-2.0f * fabsf(x));
  float t = (1.0f - e) / (1.0f + e);
  return copysignf(t, x);
}
__device__ __forceinline__ unsigned short bf16hi(float x) {
  __hip_bfloat16 h = __float2bfloat16(x);
  return *(unsigned short*)&h;
}
__device__ __forceinline__ float bf2f(unsigned short u) {
  return __uint_as_float(((unsigned)u) << 16);
}
__device__ __forceinline__ float bflo(unsigned u) { return __uint_as_float(u << 16); }
__device__ __forceinline__ float bfhi(unsigned u) { return __uint_as_float(u & 0xffff0000u); }

// DPP cross-lane add within 16-lane rows (decoder scores)
template <int CTRL>
__device__ __forceinline__ float dpp_add(float v) {
  int p = __builtin_amdgcn_update_dpp(0, __float_as_int(v), CTRL, 0xF, 0xF, true);
  return v + __int_as_float(p);
}
__device__ __forceinline__ float row_sum16(float v) {
  v = dpp_add<0xB1>(v);
  v = dpp_add<0x4E>(v);
  v = dpp_add<0x124>(v);
  v = dpp_add<0x128>(v);
  return v;
}

// split 8 consecutive fp32 into bf16 hi/lo short8 fragments
__device__ __forceinline__ void split8(const float* p, short8& hi, short8& lo) {
  #pragma unroll
  for (int i = 0; i < 8; ++i) {
    const float v = p[i];
    const unsigned short h = bf16hi(v);
    hi[i] = (short)h;
    lo[i] = (short)bf16hi(v - bf2f(h));
  }
}

// -------------------------------------------------------------------------
// Split the 3 encoder w_ih matrices into bf16 hi/lo pairs (one-time prep).
// -------------------------------------------------------------------------
__global__ __launch_bounds__(256) void prep_split(
    const float* __restrict__ w0, const float* __restrict__ w1,
    const float* __restrict__ w2,
    unsigned short* __restrict__ hi, unsigned short* __restrict__ lo)
{
  const int i = blockIdx.x * 256 + threadIdx.x;
  if (i >= 122880) return;
  float v = (i < 24576) ? w0[i] : ((i < 73728) ? w1[i - 24576] : w2[i - 73728]);
  const unsigned short h = bf16hi(v);
  hi[i] = h;
  lo[i] = bf16hi(v - bf2f(h));
}

// -------------------------------------------------------------------------
// gx = A @ W^T + b_ih for one T-chunk, split-bf16 MFMA (R6 structure).
// 128x128 tile, 4 waves, wave grid 2x2, 4x4 16-tiles per wave.
// -------------------------------------------------------------------------
__global__ __launch_bounds__(256) void gx_gemm(
    const float* __restrict__ x,
    const unsigned short* __restrict__ Ahi, const unsigned short* __restrict__ Alo,
    const unsigned short* __restrict__ Whi, const unsigned short* __restrict__ Wlo,
    const float* __restrict__ b_ih, float* __restrict__ gx,
    int t0, int k_dim, int is_layer0)
{
  __shared__ unsigned short Ah[128 * 40], Al[128 * 40];
  __shared__ unsigned short Bh[128 * 40], Bl[128 * 40];
  const int tid  = threadIdx.x;
  const int wave = tid >> 6, lane = tid & 63;
  const int quad = lane >> 4, l16 = lane & 15;
  const int m0 = blockIdx.x * 128;
  const int n0 = blockIdx.y * 128;
  const int wm = (wave & 1) * 64;
  const int wn = (wave >> 1) * 64;
  const size_t row0 = (size_t)t0 * B_SZ + m0;

  f32x4 acc[4][4];
  #pragma unroll
  for (int i = 0; i < 4; ++i)
    #pragma unroll
    for (int j = 0; j < 4; ++j) acc[i][j] = (f32x4){0.f, 0.f, 0.f, 0.f};

  float bias[4];
  #pragma unroll
  for (int nt = 0; nt < 4; ++nt) bias[nt] = b_ih[n0 + wn + nt * 16 + l16];

  for (int kc = 0; kc < k_dim; kc += 32) {
    __syncthreads();
    if (is_layer0) {
      #pragma unroll
      for (int g = tid; g < 1024; g += 256) {
        const int r = g >> 3, c4 = (g & 7) * 4;
        const int m = m0 + r;
        const int tg = t0 + (m >> 9), bb = m & 511;
        const float4 v = *(const float4*)&x[((size_t)bb * T_LEN + tg) * 64 + kc + c4];
        const unsigned short h0 = bf16hi(v.x), h1 = bf16hi(v.y),
                             h2 = bf16hi(v.z), h3 = bf16hi(v.w);
        ushort4 hv; hv.x = h0; hv.y = h1; hv.z = h2; hv.w = h3;
        ushort4 lv;
        lv.x = bf16hi(v.x - bf2f(h0)); lv.y = bf16hi(v.y - bf2f(h1));
        lv.z = bf16hi(v.z - bf2f(h2)); lv.w = bf16hi(v.w - bf2f(h3));
        *(ushort4*)&Ah[r * 40 + c4] = hv;
        *(ushort4*)&Al[r * 40 + c4] = lv;
      }
    } else {
      #pragma unroll
      for (int g = tid; g < 512; g += 256) {
        const int r = g >> 2, c8 = (g & 3) * 8;
        const size_t src = (row0 + r) * k_dim + kc + c8;
        *(uint4*)&Ah[r * 40 + c8] = *(const uint4*)&Ahi[src];
        *(uint4*)&Al[r * 40 + c8] = *(const uint4*)&Alo[src];
      }
    }
    #pragma unroll
    for (int g = tid; g < 512; g += 256) {
      const int r = g >> 2, c8 = (g & 3) * 8;
      const size_t src = (size_t)(n0 + r) * k_dim + kc + c8;
      *(uint4*)&Bh[r * 40 + c8] = *(const uint4*)&Whi[src];
      *(uint4*)&Bl[r * 40 + c8] = *(const uint4*)&Wlo[src];
    }
    __syncthreads();

    short8 ah[4], al[4], bh[4], bl[4];
    #pragma unroll
    for (int mt = 0; mt < 4; ++mt) {
      ah[mt] = *(const short8*)&Ah[(wm + mt * 16 + l16) * 40 + quad * 8];
      al[mt] = *(const short8*)&Al[(wm + mt * 16 + l16) * 40 + quad * 8];
    }
    #pragma unroll
    for (int nt = 0; nt < 4; ++nt) {
      bh[nt] = *(const short8*)&Bh[(wn + nt * 16 + l16) * 40 + quad * 8];
      bl[nt] = *(const short8*)&Bl[(wn + nt * 16 + l16) * 40 + quad * 8];
    }
    #pragma unroll
    for (int mt = 0; mt < 4; ++mt) {
      #pragma unroll
      for (int nt = 0; nt < 4; ++nt) {
        acc[mt][nt] = __builtin_amdgcn_mfma_f32_16x16x32_bf16(ah[mt], bh[nt], acc[mt][nt], 0, 0, 0);
        acc[mt][nt] = __builtin_amdgcn_mfma_f32_16x16x32_bf16(ah[mt], bl[nt], acc[mt][nt], 0, 0, 0);
        acc[mt][nt] = __builtin_amdgcn_mfma_f32_16x16x32_bf16(al[mt], bh[nt], acc[mt][nt], 0, 0, 0);
      }
    }
  }
  #pragma unroll
  for (int mt = 0; mt < 4; ++mt) {
    #pragma unroll
    for (int nt = 0; nt < 4; ++nt) {
      #pragma unroll
      for (int reg = 0; reg < 4; ++reg) {
        const int m = m0 + wm + mt * 16 + quad * 4 + reg;
        const int n = n0 + wn + nt * 16 + l16;
        gx[(size_t)m * 384 + n] = acc[mt][nt][reg] + bias[nt];
      }
    }
  }
}

// -------------------------------------------------------------------------
// MFMA recurrence: 256 blocks x 2 batch rows, 512 threads (8 waves).
// gh = h @ w_hh^T via 16x16x32 MFMA with batch rows in M-rows 0..1
// (rows 2..15 of the A-tile are zeros kept in LDS). Split-bf16 h and w
// (3 products) give fp32-grade gh. Weights live as per-wave B-fragments
// in VGPRs (wave w owns n-tiles 3w..3w+2; 24 short8 = 96 VGPR).
// No DPP reduction: C-layout leaves gh[n] in quad-0 lanes (regs 0,1).
// -------------------------------------------------------------------------
__global__ __launch_bounds__(512, 2) void rec_mfma(
    const float* __restrict__ gx,   // (T_CHUNK, B, 384), includes b_ih
    const float* __restrict__ w_hh, const float* __restrict__ b_hh,
    unsigned short* __restrict__ Hhi, unsigned short* __restrict__ Hlo,
    float* __restrict__ h_state,    // (B, 128)
    int t0, int chunk0)
{
  __shared__ unsigned short hsh[16 * 128];   // A-tile hi (rows 2-15 zero)
  __shared__ unsigned short hsl[16 * 128];   // A-tile lo
  __shared__ float ghs2[384 * 2];            // gh interleaved [n][row]
  __shared__ float gxs[2][2][384];
  __shared__ float bhl[384];

  const int tid  = threadIdx.x;
  const int wave = tid >> 6, lane = tid & 63;
  const int quad = lane >> 4, l16 = lane & 15;
  const int b0   = blockIdx.x * 2;

  // B-fragments (once per dispatch): lane holds w_hh[n][k0..k0+8) hi/lo
  short8 Bh[3][4], Bl[3][4];
  #pragma unroll
  for (int t = 0; t < 3; ++t) {
    const int n = (wave * 3 + t) * 16 + l16;
    #pragma unroll
    for (int c = 0; c < 4; ++c) {
      split8(&w_hh[(size_t)n * 128 + c * 32 + quad * 8], Bh[t][c], Bl[t][c]);
    }
  }
  if (tid < 384) bhl[tid] = b_hh[tid];
  // zero rows 2-15 of the A-tile
  for (int i = 256 + tid; i < 2048; i += 512) { hsh[i] = 0; hsl[i] = 0; }
  // init rows 0-1
  if (tid < 256) {
    const int rr = tid >> 7, c = tid & 127;
    const float h0 = chunk0 ? 0.0f : h_state[(size_t)(b0 + rr) * 128 + c];
    const unsigned short hh = bf16hi(h0);
    hsh[rr * 128 + c] = hh;
    hsl[rr * 128 + c] = bf16hi(h0 - bf2f(hh));
  }
  // gxs[0] init (768 values, tid + optional tid+512)
  const int gr0 = (tid >= 384) ? 1 : 0;
  const int gi0 = tid - gr0 * 384;
  const int gi1 = tid + 128;                 // for tid<256: index 512+tid -> row1, gi = tid+128
  if (tid < 512) gxs[0][gr0][gi0] = gx[(size_t)(b0 + gr0) * 384 + gi0];
  if (tid < 256) gxs[0][1][gi1]   = gx[(size_t)(b0 + 1) * 384 + gi1];
  __syncthreads();

  for (int tl = 0; tl < T_CHUNK; ++tl) {
    // prefetch next step's gx into registers (hidden under MFMA)
    float gxn0 = 0.0f, gxn1 = 0.0f;
    if (tl + 1 < T_CHUNK) {
      gxn0 = gx[((size_t)(tl + 1) * B_SZ + b0 + gr0) * 384 + gi0];
      if (tid < 256)
        gxn1 = gx[((size_t)(tl + 1) * B_SZ + b0 + 1) * 384 + gi1];
    }

    // A-fragments: lane row = l16 (rows>=2 read zeros)
    short8 Ah[4], Al[4];
    #pragma unroll
    for (int c = 0; c < 4; ++c) {
      const int ad = l16 * 128 + c * 32 + quad * 8;
      Ah[c] = *(const short8*)&hsh[ad];
      Al[c] = *(const short8*)&hsl[ad];
    }

    f32x4 acc[3];
    #pragma unroll
    for (int t = 0; t < 3; ++t) acc[t] = (f32x4){0.f, 0.f, 0.f, 0.f};
    #pragma unroll
    for (int c = 0; c < 4; ++c) {
      #pragma unroll
      for (int t = 0; t < 3; ++t) {
        acc[t] = __builtin_amdgcn_mfma_f32_16x16x32_bf16(Ah[c], Bh[t][c], acc[t], 0, 0, 0);
        acc[t] = __builtin_amdgcn_mfma_f32_16x16x32_bf16(Ah[c], Bl[t][c], acc[t], 0, 0, 0);
        acc[t] = __builtin_amdgcn_mfma_f32_16x16x32_bf16(Al[c], Bh[t][c], acc[t], 0, 0, 0);
      }
    }
    // rows 0,1 live in quad-0 lanes, regs 0,1
    if (quad == 0) {
      #pragma unroll
      for (int t = 0; t < 3; ++t) {
        const int n = (wave * 3 + t) * 16 + l16;
        *(float2*)&ghs2[n * 2] = make_float2(acc[t][0], acc[t][1]);
      }
    }
    // stash gx prefetch
    const int nb = (tl + 1) & 1;
    gxs[nb][gr0][gi0] = gxn0;
    if (tid < 256) gxs[nb][1][gi1] = gxn1;
    __syncthreads();

    // gates (256 threads)
    if (tid < 256) {
      const int rr = tid >> 7, c = tid & 127;
      const float* gxp = gxs[tl & 1][rr];
      const float gh_r = ghs2[c * 2 + rr];
      const float gh_z = ghs2[(c + 128) * 2 + rr];
      const float gh_n = ghs2[(c + 256) * 2 + rr];
      const float h_old = bf2f(hsh[rr * 128 + c]) + bf2f(hsl[rr * 128 + c]);
      const float rg = fsig(gxp[c]       + gh_r + bhl[c]);
      const float zg = fsig(gxp[128 + c] + gh_z + bhl[128 + c]);
      const float ng = ftanh(gxp[256 + c] + rg * (gh_n + bhl[256 + c]));
      const float hn = (1.0f - zg) * ng + zg * h_old;
      const unsigned short hh = bf16hi(hn);
      const unsigned short hl = bf16hi(hn - bf2f(hh));
      hsh[rr * 128 + c] = hh;
      hsl[rr * 128 + c] = hl;
      const size_t ob = ((size_t)(t0 + tl) * B_SZ + (b0 + rr)) * 128 + c;
      Hhi[ob] = hh;
      Hlo[ob] = hl;
    }
    __syncthreads();
  }
  if (tid < 256) {
    const int rr = tid >> 7, c = tid & 127;
    h_state[(size_t)(b0 + rr) * 128 + c] =
        bf2f(hsh[rr * 128 + c]) + bf2f(hsl[rr * 128 + c]);
  }
}

// -------------------------------------------------------------------------
// keys = H @ aWk^T + abk, split-bf16 MFMA, output Khi (bf16 RNE) only.
// -------------------------------------------------------------------------
__global__ __launch_bounds__(256) void keys_gemm(
    const unsigned short* __restrict__ Ahi, const unsigned short* __restrict__ Alo,
    const float* __restrict__ aWk, const float* __restrict__ abk,
    unsigned short* __restrict__ Khi)
{
  __shared__ unsigned short Ah[64 * 40], Al[64 * 40];
  __shared__ unsigned short Bh[128 * 136], Bl[128 * 136];
  const int tid  = threadIdx.x;
  const int wave = tid >> 6, lane = tid & 63;
  const int quad = lane >> 4, l16 = lane & 15;
  const size_t m0 = (size_t)blockIdx.x * 64;

  for (int i = tid; i < 16384; i += 256) {
    const float v = aWk[i];
    const unsigned short h = bf16hi(v);
    const int r = i >> 7, k = i & 127;
    Bh[r * 136 + k] = h;
    Bl[r * 136 + k] = bf16hi(v - bf2f(h));
  }

  f32x4 acc[8];
  #pragma unroll
  for (int i = 0; i < 8; ++i) acc[i] = (f32x4){0.f, 0.f, 0.f, 0.f};
  float bias[8];
  #pragma unroll
  for (int nt = 0; nt < 8; ++nt) bias[nt] = abk[nt * 16 + l16];

  const int r = tid >> 2, c8 = (tid & 3) * 8;
  for (int kc = 0; kc < 128; kc += 32) {
    __syncthreads();
    const size_t src = (m0 + r) * 128 + kc + c8;
    *(uint4*)&Ah[r * 40 + c8] = *(const uint4*)&Ahi[src];
    *(uint4*)&Al[r * 40 + c8] = *(const uint4*)&Alo[src];
    __syncthreads();
    const short8 a_hi = *(const short8*)&Ah[(wave * 16 + l16) * 40 + quad * 8];
    const short8 a_lo = *(const short8*)&Al[(wave * 16 + l16) * 40 + quad * 8];
    #pragma unroll
    for (int nt = 0; nt < 8; ++nt) {
      const short8 b_hi = *(const short8*)&Bh[(nt * 16 + l16) * 136 + kc + quad * 8];
      const short8 b_lo = *(const short8*)&Bl[(nt * 16 + l16) * 136 + kc + quad * 8];
      acc[nt] = __builtin_amdgcn_mfma_f32_16x16x32_bf16(a_hi, b_hi, acc[nt], 0, 0, 0);
      acc[nt] = __builtin_amdgcn_mfma_f32_16x16x32_bf16(a_hi, b_lo, acc[nt], 0, 0, 0);
      acc[nt] = __builtin_amdgcn_mfma_f32_16x16x32_bf16(a_lo, b_hi, acc[nt], 0, 0, 0);
    }
  }
  #pragma unroll
  for (int nt = 0; nt < 8; ++nt) {
    #pragma unroll
    for (int reg = 0; reg < 4; ++reg) {
      const size_t m = m0 + wave * 16 + quad * 4 + reg;
      const int n = nt * 16 + l16;
      Khi[m * 128 + n] = bf16hi(acc[nt][reg] + bias[nt]);
    }
  }
}

// -------------------------------------------------------------------------
// Decoder (R7): one block per batch row, 512 threads, 8 steps in-kernel.
// K (bf16) and H (bf16-hi for ctx, hi+lo for h0) in (T,B,H).
// -------------------------------------------------------------------------
__global__ __launch_bounds__(512) void decoder(
    const unsigned short* __restrict__ Hhi, const unsigned short* __restrict__ Hlo,
    const unsigned short* __restrict__ Khi,
    const float* __restrict__ aWq, const float* __restrict__ abq,
    const float* __restrict__ av,
    const float* __restrict__ dwih, const float* __restrict__ dwhh,
    const float* __restrict__ dbih, const float* __restrict__ dbhh,
    const float* __restrict__ lng, const float* __restrict__ lnb,
    const float* __restrict__ w1, const float* __restrict__ b1,
    const float* __restrict__ w2, const float* __restrict__ b2,
    float* __restrict__ out)
{
  __shared__ float h_s[128], q_s[128], av_s[128], s_s[512], w_s[512];
  __shared__ float part[8][128], u_s[256], gx_s[384], gh_s[384], y_s[128];
  __shared__ float red[16];
  const int b = blockIdx.x, tid = threadIdx.x;
  const int wave = tid >> 6, lane = tid & 63;
  const int tslot = lane >> 4, ks = lane & 15;

  if (tid < 128) {
    const size_t base = ((size_t)(T_LEN - 1) * B_SZ + b) * 128 + tid;
    h_s[tid] = bf2f(Hhi[base]) + bf2f(Hlo[base]);
    av_s[tid] = av[tid];
  }
  __syncthreads();

  for (int step = 0; step < NSTEP; ++step) {
    if (tid < 128) {
      float acc = abq[tid];
      const float* wr = &aWq[(size_t)tid * 128];
      #pragma unroll 8
      for (int k4 = 0; k4 < 32; ++k4) {
        const float4 hv = *(const float4*)&h_s[k4 * 4];
        const float4 wv = *(const float4*)&wr[k4 * 4];
        acc += hv.x * wv.x + hv.y * wv.y + hv.z * wv.z + hv.w * wv.w;
      }
      q_s[tid] = acc;
    }
    __syncthreads();
    #pragma unroll 2
    for (int it = 0; it < 16; ++it) {
      const int t = it * 32 + wave * 4 + tslot;
      const size_t kb = ((size_t)t * B_SZ + b) * 128 + ks * 8;
      const uint4 uh = *(const uint4*)&Khi[kb];
      const float4 q0 = *(const float4*)&q_s[ks * 8];
      const float4 q1 = *(const float4*)&q_s[ks * 8 + 4];
      const float4 a0 = *(const float4*)&av_s[ks * 8];
      const float4 a1 = *(const float4*)&av_s[ks * 8 + 4];
      float acc = ftanh(bflo(uh.x) + q0.x) * a0.x + ftanh(bfhi(uh.x) + q0.y) * a0.y
                + ftanh(bflo(uh.y) + q0.z) * a0.z + ftanh(bfhi(uh.y) + q0.w) * a0.w
                + ftanh(bflo(uh.z) + q1.x) * a1.x + ftanh(bfhi(uh.z) + q1.y) * a1.y
                + ftanh(bflo(uh.w) + q1.z) * a1.z + ftanh(bfhi(uh.w) + q1.w) * a1.w;
      acc = row_sum16(acc);
      if (ks == 0) s_s[t] = acc;
    }
    __syncthreads();
    {
      const float sv = s_s[tid];
      float mx = sv;
      #pragma unroll
      for (int o = 32; o; o >>= 1) mx = fmaxf(mx, __shfl_xor(mx, o, 64));
      if (lane == 0) red[wave] = mx;
      __syncthreads();
      mx = red[0];
      #pragma unroll
      for (int i = 1; i < 8; ++i) mx = fmaxf(mx, red[i]);
      const float e = __expf(sv - mx);
      float sm = e;
      #pragma unroll
      for (int o = 32; o; o >>= 1) sm += __shfl_xor(sm, o, 64);
      if (lane == 0) red[8 + wave] = sm;
      __syncthreads();
      float tot = red[8];
      #pragma unroll
      for (int i = 1; i < 8; ++i) tot += red[8 + i];
      w_s[tid] = e / tot;
    }
    __syncthreads();
    {
      const int th = tid >> 6;
      const int c2 = (tid & 63) * 2;
      float acc0 = 0.0f, acc1 = 0.0f;
      #pragma unroll 4
      for (int q = 0; q < 64; ++q) {
        const int t = th * 64 + q;
        const unsigned u = *(const unsigned*)&Hhi[((size_t)t * B_SZ + b) * 128 + c2];
        const float wt = w_s[t];
        acc0 += wt * bflo(u);
        acc1 += wt * bfhi(u);
      }
      part[th][c2] = acc0;
      part[th][c2 + 1] = acc1;
    }
    __syncthreads();
    if (tid < 128) {
      float s = part[0][tid];
      #pragma unroll
      for (int i = 1; i < 8; ++i) s += part[i][tid];
      u_s[tid] = s;
      u_s[128 + tid] = h_s[tid];
    }
    __syncthreads();
    if (tid < 384) {
      const int j = tid;
      float gxv = dbih[j], ghv = dbhh[j];
      const float* wxr = &dwih[(size_t)j * 256];
      const float* whr = &dwhh[(size_t)j * 128];
      #pragma unroll 8
      for (int k4 = 0; k4 < 64; ++k4) {
        const float4 uv = *(const float4*)&u_s[k4 * 4];
        const float4 wv = *(const float4*)&wxr[k4 * 4];
        gxv += uv.x * wv.x + uv.y * wv.y + uv.z * wv.z + uv.w * wv.w;
      }
      #pragma unroll 8
      for (int k4 = 0; k4 < 32; ++k4) {
        const float4 hv = *(const float4*)&h_s[k4 * 4];
        const float4 wv = *(const float4*)&whr[k4 * 4];
        ghv += hv.x * wv.x + hv.y * wv.y + hv.z * wv.z + hv.w * wv.w;
      }
      gx_s[j] = gxv; gh_s[j] = ghv;
    }
    __syncthreads();
    if (tid < 128) {
      const float r = fsig(gx_s[tid] + gh_s[tid]);
      const float z = fsig(gx_s[128 + tid] + gh_s[128 + tid]);
      const float n = ftanh(gx_s[256 + tid] + r * gh_s[256 + tid]);
      const float hn = (1.0f - z) * n + z * h_s[tid];
      h_s[tid] = hn;
      float s1 = hn, s2 = hn * hn;
      #pragma unroll
      for (int o = 32; o; o >>= 1) { s1 += __shfl_xor(s1, o, 64); s2 += __shfl_xor(s2, o, 64); }
      if ((tid & 63) == 0) { red[tid >> 6] = s1; red[4 + (tid >> 6)] = s2; }
    }
    __syncthreads();
    if (tid < 128) {
      const float hn  = h_s[tid];
      const float mu  = (red[0] + red[1]) * (1.0f / 128.0f);
      const float var = (red[4] + red[5]) * (1.0f / 128.0f) - mu * mu;
      y_s[tid] = (hn - mu) / sqrtf(var + 1e-5f) * lng[tid] + lnb[tid];
    }
    __syncthreads();
    if (tid < 64) {
      float acc = b1[tid];
      const float* wr = &w1[(size_t)tid * 128];
      #pragma unroll 8
      for (int k4 = 0; k4 < 32; ++k4) {
        const float4 yv = *(const float4*)&y_s[k4 * 4];
        const float4 wv = *(const float4*)&wr[k4 * 4];
        acc += yv.x * wv.x + yv.y * wv.y + yv.z * wv.z + yv.w * wv.w;
      }
      acc = fmaxf(acc, 0.0f);
      float v = acc * w2[tid];
      #pragma unroll
      for (int o = 32; o; o >>= 1) v += __shfl_xor(v, o, 64);
      if (tid == 0) out[(size_t)b * NSTEP + step] = v + b2[0];
    }
    __syncthreads();
  }
}

// -------------------------------------------------------------------------
extern "C" void kernel_launch(void* const* d_in, const int* in_sizes, int n_in,
                              void* d_out, int out_size, void* d_ws, size_t ws_size,
                              hipStream_t stream)
{
  (void)in_sizes; (void)n_in; (void)out_size; (void)ws_size;
  const float* x    = (const float*)d_in[0];
  const float* ewih[3] = {(const float*)d_in[1], (const float*)d_in[5], (const float*)d_in[9]};
  const float* ewhh[3] = {(const float*)d_in[2], (const float*)d_in[6], (const float*)d_in[10]};
  const float* ebih[3] = {(const float*)d_in[3], (const float*)d_in[7], (const float*)d_in[11]};
  const float* ebhh[3] = {(const float*)d_in[4], (const float*)d_in[8], (const float*)d_in[12]};
  const float* aWq  = (const float*)d_in[13];
  const float* abq  = (const float*)d_in[14];
  const float* aWk  = (const float*)d_in[15];
  const float* abk  = (const float*)d_in[16];
  const float* av   = (const float*)d_in[17];
  const float* dwih = (const float*)d_in[18];
  const float* dwhh = (const float*)d_in[19];
  const float* dbih = (const float*)d_in[20];
  const float* dbhh = (const float*)d_in[21];
  const float* lng  = (const float*)d_in[22];
  const float* lnb  = (const float*)d_in[23];
  const float* w1   = (const float*)d_in[24];
  const float* b1   = (const float*)d_in[25];
  const float* w2   = (const float*)d_in[26];
  const float* b2   = (const float*)d_in[27];

  const size_t HN = (size_t)T_LEN * B_SZ * H_DIM;               // 33,554,432 elems
  unsigned short* Hhi = (unsigned short*)d_ws;                  // 64 MiB (T,B,H)
  unsigned short* Hlo = Hhi + HN;                               // 64 MiB
  float* regionC = (float*)(Hlo + HN);                          // 128 MiB
  float* gxc     = regionC;                                     // 96 MiB
  float* h_state = regionC + 25165824;
  unsigned short* Whi = (unsigned short*)(h_state + 65536);
  unsigned short* Wlo = Whi + 122880;
  unsigned short* Khi = (unsigned short*)regionC;               // decode: 64 MiB

  prep_split<<<dim3(480), dim3(256), 0, stream>>>(ewih[0], ewih[1], ewih[2], Whi, Wlo);

  const int koff[3] = {0, 24576, 73728};
  const int kdim[3] = {64, 128, 128};
  for (int l = 0; l < 3; ++l) {
    for (int c = 0; c < 4; ++c) {
      const int t0 = c * T_CHUNK;
      gx_gemm<<<dim3(512, 3), dim3(256), 0, stream>>>(
          x, Hhi, Hlo, Whi + koff[l], Wlo + koff[l], ebih[l],
          gxc, t0, kdim[l], (l == 0) ? 1 : 0);
      rec_mfma<<<dim3(256), dim3(512), 0, stream>>>(
          gxc, ewhh[l], ebhh[l], Hhi, Hlo, h_state, t0, (c == 0) ? 1 : 0);
    }
  }

  keys_gemm<<<dim3(4096), dim3(256), 0, stream>>>(Hhi, Hlo, aWk, abk, Khi);
  decoder<<<dim3(512), dim3(512), 0, stream>>>(
      Hhi, Hlo, Khi, aWq, abq, av, dwih, dwhh, dbih, dbhh,
      lng, lnb, w1, b1, w2, b2, (float*)d_out);
}